// Round 5
// baseline (437.889 us; speedup 1.0000x reference)
//
#include <hip/hip_runtime.h>

#define BATCH 64
#define HH 512
#define WW 512
#define TH 32          // output rows per block strip
#define KS 11
#define PADK 5
#define LROW (WW + 2 * PADK)   // 522 float2 slots per row
#define NT 512                 // 1 column per thread
#define NBLK ((HH / TH) * BATCH)   // 1024 blocks
#define NPIX (64.0 * 512.0 * 512.0)

// One block: 512 threads = one image row width; strip of TH=32 output rows.
// Staged rows i=0..43 (42 real + 2 dummy) in 2-row double-buffered float2{a,b}
// chunks (22 barriers). Per row: 11 ds_read_b64, on-the-fly q=a^2+b^2, p=ab,
// horizontal 11-tap -> h1,h2,hq,hp; DISTRIBUTED vertical accumulators:
//   acc[(i-t)%11] (+)= G[t]*h   (t=0 initializes with a mul -> no resets)
// Output j completes at row i=j+10 -> SSIM -> local sum. Slot indices static
// via 22-row groups (22 % 11 == 0) with dynamic 2-iter outer loop.
// Register budget: 44 acc + ~35 misc; amdgpu_waves_per_eu(4) -> cap 128 VGPR
// (R3/R4 lesson: launch_bounds min-arg produced 64/84-VGPR caps -> 53-62 MB
// scratch spill traffic; avoid it).
__global__ void __launch_bounds__(NT)
__attribute__((amdgpu_waves_per_eu(4)))
ssim_main_kernel(const float* __restrict__ img1, const float* __restrict__ img2,
                 double* __restrict__ accum, unsigned int* __restrict__ counter,
                 float* __restrict__ out) {
  // Gaussian(sigma=1.5, K=11), normalized (fp64-precomputed).
  constexpr float G[KS] = {
      0.00102838f, 0.00759884f, 0.03600087f, 0.10936069f, 0.21300553f,
      0.26601172f, 0.21300553f, 0.10936069f, 0.03600087f, 0.00759884f,
      0.00102838f};

  const int c  = threadIdx.x;            // column 0..511
  const int r0 = blockIdx.x * TH;
  const int b  = blockIdx.y;

  const float* __restrict__ p1 = img1 + (size_t)b * (HH * WW);
  const float* __restrict__ p2 = img2 + (size_t)b * (HH * WW);

  // Double-buffered 2-row chunks, zero-padded horizontally (16.7 KB).
  __shared__ float2 sh[2][2][LROW];
  if (c < PADK) {
#pragma unroll
    for (int bi = 0; bi < 2; ++bi)
#pragma unroll
      for (int r = 0; r < 2; ++r) {
        sh[bi][r][c]             = make_float2(0.f, 0.f);
        sh[bi][r][WW + PADK + c] = make_float2(0.f, 0.f);
      }
  }

  // Distributed vertical accumulators: slot j%11 belongs to output row j,
  // live from staged row i=j (init) to i=j+10 (complete).
  float aA[KS], aB[KS], aQ[KS], aP[KS];
  float local = 0.f;

  // Prefetch chunk 0 (staged rows 0,1 -> image rows r0-5, r0-4).
  float pa0, pb0, pa1, pb1;
  {
    const int rr0 = r0 - PADK;
    const int rr1 = rr0 + 1;
    pa0 = (rr0 >= 0) ? p1[rr0 * WW + c] : 0.f;
    pb0 = (rr0 >= 0) ? p2[rr0 * WW + c] : 0.f;
    pa1 = (rr1 >= 0) ? p1[rr1 * WW + c] : 0.f;
    pb1 = (rr1 >= 0) ? p2[rr1 * WW + c] : 0.f;
  }

  for (int g = 0; g < 2; ++g) {          // dynamic outer: code stays ~13 KB
    const int ibase = 22 * g;
    // Chunk parity: buf = (11g + k) & 1 -> even k uses sh[g&1], odd the other.
    float2 (*bufE)[LROW] = sh[g & 1];
    float2 (*bufO)[LROW] = sh[1 - (g & 1)];
#pragma unroll
    for (int k = 0; k < KS; ++k) {       // 11 chunks x 2 rows = 22 rows/group
      float2 (*B)[LROW] = (k & 1) ? bufO : bufE;   // static select

      // Stage chunk from prefetch regs (conflict-free stride-8 b64 writes).
      B[0][PADK + c] = make_float2(pa0, pb0);
      B[1][PADK + c] = make_float2(pa1, pb1);
      __syncthreads();                   // one barrier per 2 rows

      // Prefetch next chunk (rows i0+2, i0+3); bounds-guarded (uniform).
      {
        const int rr  = r0 - PADK + ibase + 2 * k + 2;
        const int rr1 = rr + 1;
        const bool v0 = (rr  >= 0) && (rr  < HH);
        const bool v1 = (rr1 >= 0) && (rr1 < HH);
        pa0 = v0 ? p1[rr  * WW + c] : 0.f;
        pb0 = v0 ? p2[rr  * WW + c] : 0.f;
        pa1 = v1 ? p1[rr1 * WW + c] : 0.f;
        pb1 = v1 ? p2[rr1 * WW + c] : 0.f;
      }

      if (ibase + 2 * k < TH + 2 * PADK) {   // skip dummy rows 42,43
#pragma unroll
        for (int r = 0; r < 2; ++r) {
          // Horizontal 11-tap conv of {a, b, q=a^2+b^2, p=ab} on the fly.
          float h1 = 0.f, h2 = 0.f, hq = 0.f, hp = 0.f;
#pragma unroll
          for (int k2 = 0; k2 < KS; ++k2) {
            const float2 v = B[r][c + k2];
            const float q  = fmaf(v.x, v.x, v.y * v.y);
            const float pp = v.x * v.y;
            h1 = fmaf(G[k2], v.x, h1);
            h2 = fmaf(G[k2], v.y, h2);
            hq = fmaf(G[k2], q,   hq);
            hp = fmaf(G[k2], pp,  hp);
          }

          // t=0: init slot i%11 (output j=i). Safe unguarded: previous
          // occupant (j=i-11) completed at row i-1.
          const int s0 = (2 * k + r) % KS;         // static
          aA[s0] = G[0] * h1; aB[s0] = G[0] * h2;
          aQ[s0] = G[0] * hq; aP[s0] = G[0] * hp;

          // t=1..10: update pending outputs j=i-t. Unguarded garbage at
          // edges lands only in slots re-initialized before valid use.
#pragma unroll
          for (int t = 1; t < KS; ++t) {
            const int s = (2 * k + r - t + 22) % KS;   // static
            aA[s] = fmaf(G[t], h1, aA[s]);
            aB[s] = fmaf(G[t], h2, aB[s]);
            aQ[s] = fmaf(G[t], hq, aQ[s]);
            aP[s] = fmaf(G[t], hp, aP[s]);
          }

          // Output j=i-10 just completed (slot (i+1)%11).
          const int i = ibase + 2 * k + r;
          if (i >= 2 * PADK && i < TH + 2 * PADK) {  // uniform scalar branch
            const int s = (2 * k + r + 1) % KS;      // static
            const float mu1 = aA[s], mu2 = aB[s];
            const float m1s = mu1 * mu1, m2s = mu2 * mu2, m12 = mu1 * mu2;
            const float t12 = m1s + m2s;
            const float s12 = aP[s] - m12;
            const float sqq = aQ[s] - t12;
            const float C1 = 1e-4f, C2 = 9e-4f;
            const float num = fmaf(2.f, m12, C1) * fmaf(2.f, s12, C2);
            const float den = (t12 + C1) * (sqq + C2);
            local = fmaf(num, __builtin_amdgcn_rcpf(den), local);
          }
        }
      }
    }
  }

  // Block reduction: wave64 shuffle -> LDS -> one atomic per block.
#pragma unroll
  for (int off = 32; off > 0; off >>= 1) local += __shfl_down(local, off, 64);

  __shared__ float wsum[NT / 64];
  const int wave = threadIdx.x >> 6;
  const int lane = threadIdx.x & 63;
  if (lane == 0) wsum[wave] = local;
  __syncthreads();
  if (threadIdx.x == 0) {
    float s = 0.f;
#pragma unroll
    for (int w = 0; w < NT / 64; ++w) s += wsum[w];
    atomicAdd(accum, (double)s);
    __threadfence();
    const unsigned int n = atomicAdd(counter, 1u);
    if (n == NBLK - 1) {                 // last block finalizes (saves a launch)
      __threadfence();
      const double tot = atomicAdd(accum, 0.0);  // device-scope atomic read
      out[0] = 1.0f - (float)(tot / NPIX);
    }
  }
}

extern "C" void kernel_launch(void* const* d_in, const int* in_sizes, int n_in,
                              void* d_out, int out_size, void* d_ws, size_t ws_size,
                              hipStream_t stream) {
  const float* img1 = (const float*)d_in[0];
  const float* img2 = (const float*)d_in[1];
  double* accum = (double*)d_ws;
  unsigned int* counter = (unsigned int*)((char*)d_ws + sizeof(double));
  hipMemsetAsync(d_ws, 0, 16, stream);

  dim3 grid(HH / TH, BATCH);
  ssim_main_kernel<<<grid, NT, 0, stream>>>(img1, img2, accum, counter,
                                            (float*)d_out);
}

// Round 6
// 221.771 us; speedup vs baseline: 1.9745x; 1.9745x over previous
//
#include <hip/hip_runtime.h>

#define BATCH 64
#define HH 512
#define WW 512
#define TH 32          // output rows per block strip
#define KS 11
#define PADK 5
#define LROW (WW + 2 * PADK)   // 522 float2 slots per row
#define NT 512                 // 1 column per thread
#define NBLK ((HH / TH) * BATCH)
#define NPIX (64.0 * 512.0 * 512.0)

// R2 skeleton (proven no-spill: write-once ring -> AGPRs) + 4-signal reform
// + 2-row chunks (21 barriers vs 42).
// Per staged row: 11 ds_read_b64 of float2{a,b}; per tap compute q=a^2+b^2,
// p=ab in-flight; horizontal 11-tap -> (h1,h2,hq,hp); ring slot i%11 written
// ONCE (AGPR-friendly; R5 lesson: RMW accumulators spill to scratch, 680 MB).
// Vertical 11-tap reads all 11 slots with static indices.
// No launch_bounds min-arg / waves_per_eu (R3/R4/R5 lesson: they produced
// 64-84 VGPR caps and 53-680 MB scratch traffic).
__global__ void __launch_bounds__(NT)
ssim_main_kernel(const float* __restrict__ img1, const float* __restrict__ img2,
                 double* __restrict__ accum, unsigned int* __restrict__ counter,
                 float* __restrict__ out) {
  // Gaussian(sigma=1.5, K=11), normalized (fp64-precomputed).
  constexpr float G[KS] = {
      0.00102838f, 0.00759884f, 0.03600087f, 0.10936069f, 0.21300553f,
      0.26601172f, 0.21300553f, 0.10936069f, 0.03600087f, 0.00759884f,
      0.00102838f};

  const int c  = threadIdx.x;            // column 0..511
  const int r0 = blockIdx.x * TH;
  const int b  = blockIdx.y;

  const float* __restrict__ p1 = img1 + (size_t)b * (HH * WW);
  const float* __restrict__ p2 = img2 + (size_t)b * (HH * WW);

  // Double-buffered 2-row chunks, zero-padded horizontally (16.7 KB).
  __shared__ float2 sh[2][2][LROW];
  if (c < PADK) {
#pragma unroll
    for (int bi = 0; bi < 2; ++bi)
#pragma unroll
      for (int r = 0; r < 2; ++r) {
        sh[bi][r][c]             = make_float2(0.f, 0.f);
        sh[bi][r][WW + PADK + c] = make_float2(0.f, 0.f);
      }
  }

  // Ring: slot (i % 11) holds h-conv of staged row i. Write-once, read-11x.
  float rA[KS], rB[KS], rQ[KS], rP[KS];
  float local = 0.f;

  // Prefetch chunk 0 (staged rows 0,1 -> image rows r0-5, r0-4).
  float pa0, pb0, pa1, pb1;
  {
    const int rr0 = r0 - PADK;
    const int rr1 = rr0 + 1;
    pa0 = (rr0 >= 0) ? p1[rr0 * WW + c] : 0.f;
    pb0 = (rr0 >= 0) ? p2[rr0 * WW + c] : 0.f;
    pa1 = (rr1 >= 0) ? p1[rr1 * WW + c] : 0.f;
    pb1 = (rr1 >= 0) ? p2[rr1 * WW + c] : 0.f;
  }

  for (int g = 0; g < 2; ++g) {          // dynamic outer: code fits I$
    float2 (*bufE)[LROW] = sh[g & 1];    // chunk parity across g boundary
    float2 (*bufO)[LROW] = sh[1 - (g & 1)];
#pragma unroll
    for (int k = 0; k < KS; ++k) {       // 11 chunks x 2 rows per group
      if (!(g == 1 && k == KS - 1)) {    // rows 42,43 feed nothing: skip
        float2 (*B)[LROW] = (k & 1) ? bufO : bufE;   // static select

        // Stage chunk from prefetch regs (conflict-free b64 writes).
        B[0][PADK + c] = make_float2(pa0, pb0);
        B[1][PADK + c] = make_float2(pa1, pb1);
        __syncthreads();                 // one barrier per 2 rows

        // Prefetch next chunk (staged rows i2, i2+1), skip past row 41.
        if (22 * g + 2 * k + 2 < TH + 2 * PADK) {
          const int rr  = r0 - PADK + 22 * g + 2 * k + 2;
          const int rr1 = rr + 1;
          const bool v0 = (rr  >= 0) && (rr  < HH);
          const bool v1 = (rr1 >= 0) && (rr1 < HH);
          pa0 = v0 ? p1[rr  * WW + c] : 0.f;
          pb0 = v0 ? p2[rr  * WW + c] : 0.f;
          pa1 = v1 ? p1[rr1 * WW + c] : 0.f;
          pb1 = v1 ? p2[rr1 * WW + c] : 0.f;
        }

#pragma unroll
        for (int r = 0; r < 2; ++r) {
          const int s0 = (2 * k + r) % KS;           // static slot

          // Horizontal 11-tap of {a, b, q=a^2+b^2, p=ab} (q,p in-flight).
          float h1 = 0.f, h2 = 0.f, hq = 0.f, hp = 0.f;
#pragma unroll
          for (int k2 = 0; k2 < KS; ++k2) {
            const float2 v = B[r][c + k2];
            const float q  = fmaf(v.x, v.x, v.y * v.y);
            const float pp = v.x * v.y;
            h1 = fmaf(G[k2], v.x, h1);
            h2 = fmaf(G[k2], v.y, h2);
            hq = fmaf(G[k2], q,  hq);
            hp = fmaf(G[k2], pp, hp);
          }
          rA[s0] = h1; rB[s0] = h2; rQ[s0] = hq; rP[s0] = hp;

          // Output j = i-10 completes now (i = 22g+2k+r; i<42 structural).
          if (22 * g + 2 * k + r >= 2 * PADK) {      // uniform scalar branch
            float mu1 = 0.f, mu2 = 0.f, mq = 0.f, mp = 0.f;
#pragma unroll
            for (int t = 0; t < KS; ++t) {
              const int s = (2 * k + r + 1 + t) % KS;  // static
              mu1 = fmaf(G[t], rA[s], mu1);
              mu2 = fmaf(G[t], rB[s], mu2);
              mq  = fmaf(G[t], rQ[s], mq);
              mp  = fmaf(G[t], rP[s], mp);
            }
            const float m1s = mu1 * mu1, m2s = mu2 * mu2, m12 = mu1 * mu2;
            const float t12 = m1s + m2s;
            const float s12 = mp - m12;          // sigma12
            const float sqq = mq - t12;          // sigma1^2 + sigma2^2
            const float C1 = 1e-4f, C2 = 9e-4f;
            const float num = fmaf(2.f, m12, C1) * fmaf(2.f, s12, C2);
            const float den = (t12 + C1) * (sqq + C2);
            local = fmaf(num, __builtin_amdgcn_rcpf(den), local);
          }
        }
      }
    }
  }

  // Block reduction: wave64 shuffle -> LDS -> one atomic per block.
#pragma unroll
  for (int off = 32; off > 0; off >>= 1) local += __shfl_down(local, off, 64);

  __shared__ float wsum[NT / 64];
  const int wave = threadIdx.x >> 6;
  const int lane = threadIdx.x & 63;
  if (lane == 0) wsum[wave] = local;
  __syncthreads();
  if (threadIdx.x == 0) {
    float s = 0.f;
#pragma unroll
    for (int w = 0; w < NT / 64; ++w) s += wsum[w];
    atomicAdd(accum, (double)s);
    __threadfence();
    const unsigned int n = atomicAdd(counter, 1u);
    if (n == NBLK - 1) {                 // last block finalizes (R5: verified)
      __threadfence();
      const double tot = atomicAdd(accum, 0.0);  // device-scope read
      out[0] = 1.0f - (float)(tot / NPIX);
    }
  }
}

extern "C" void kernel_launch(void* const* d_in, const int* in_sizes, int n_in,
                              void* d_out, int out_size, void* d_ws, size_t ws_size,
                              hipStream_t stream) {
  const float* img1 = (const float*)d_in[0];
  const float* img2 = (const float*)d_in[1];
  double* accum = (double*)d_ws;
  unsigned int* counter = (unsigned int*)((char*)d_ws + sizeof(double));
  hipMemsetAsync(d_ws, 0, 16, stream);

  dim3 grid(HH / TH, BATCH);
  ssim_main_kernel<<<grid, NT, 0, stream>>>(img1, img2, accum, counter,
                                            (float*)d_out);
}